// Round 4
// baseline (1714.942 us; speedup 1.0000x reference)
//
#include <hip/hip_runtime.h>
#include <hip/hip_bf16.h>
#include <math.h>

typedef __attribute__((ext_vector_type(8))) _Float16 half8;
typedef __attribute__((ext_vector_type(4))) float f32x4;
typedef __attribute__((ext_vector_type(4))) unsigned int u32x4;

#define FDIM 128
#define ZK 320        // padded K (297 -> 320)
#define BM 64         // edges per block
#define BKC 32        // k elems per chunk
#define NCHUNK 10     // 320/32
#define EPSBN 1e-5f
#define HSCALE_INV 0.015625f   // 1/64 : z h-columns stored as h/64
#define WSCALE 64.0f           // matching weight-row scale (exact pow2)

// ---------------- weight prep: combined, transposed, interleaved, pre-swizzled fp16 ----
// Layout: Wg[i][c][col][kk] ; i=0..5 layer, c=0..9 k-chunk(32), col=0..255, kk=0..31
// col -> (part p=(col>>4)&1, feature f=((col>>5)<<4)|(col&15)) ; p=0 -> Wf, p=1 -> Ws
// swizzle: stored kk holds source k = c*32 + (kk ^ ((col&3)<<3))
// rows k<256 (h part) pre-scaled by 64 to pair with z stored as h/64 (exact pow2)
__global__ void prep_w(const float* __restrict__ Wf, const float* __restrict__ Ws,
                       _Float16* __restrict__ Wg) {
    int idx = blockIdx.x * 256 + threadIdx.x;
    const int total = 6 * NCHUNK * 256 * BKC;
    if (idx >= total) return;
    int kk = idx & 31;
    int col = (idx >> 5) & 255;
    int t2 = idx >> 13;
    int c = t2 % NCHUNK;
    int i = t2 / NCHUNK;
    int ksrc = c * BKC + (kk ^ ((col & 3) << 3));
    int p = (col >> 4) & 1;
    int f = ((col >> 5) << 4) | (col & 15);
    float v = 0.0f;
    if (ksrc < 297) {
        size_t o = ((size_t)i * 297 + ksrc) * 128 + f;
        v = p ? Ws[o] : Wf[o];
        if (ksrc < 256) v *= WSCALE;
    }
    Wg[idx] = (_Float16)v;
}

// ---------------- embed: h = x @ embed_W + b ----------------
__global__ void embed_k(const float* __restrict__ x, const float* __restrict__ W,
                        const float* __restrict__ b, float* __restrict__ h,
                        _Float16* __restrict__ hhf, int N) {
    int n = blockIdx.x * 2 + (threadIdx.x >> 7);
    int f = threadIdx.x & 127;
    if (n >= N) return;
    float acc = b[f];
    const float* xr = x + (size_t)n * 98;
    #pragma unroll 7
    for (int k = 0; k < 98; ++k) acc = fmaf(xr[k], W[k * 128 + f], acc);
    h[(size_t)n * 128 + f] = acc;
    hhf[(size_t)n * 128 + f] = (_Float16)(acc * HSCALE_INV);
}

// ---------------- fused gather + dual GEMM + gate + scatter-add ----------------
__global__ __launch_bounds__(256, 2)
void edge_gemm(const _Float16* __restrict__ hhf,         // [N][128] fp16 (h/64)
               const float* __restrict__ ea,             // [E][41]
               const int* __restrict__ srcI, const int* __restrict__ dstI,
               const _Float16* __restrict__ WgL,         // layer base [10][256][32]
               const float* __restrict__ biasF, const float* __restrict__ biasS,
               float* __restrict__ agg) {
    __shared__ __align__(16) _Float16 zs[BM * ZK];      // 40 KB, swizzled
    __shared__ __align__(16) _Float16 wt[256 * BKC];    // 16 KB, swizzled
    __shared__ int dstl[BM];

    const int tid = threadIdx.x;
    const int eb = blockIdx.x * BM;

    if (tid < BM) dstl[tid] = dstI[eb + tid];

    // ---- stage z tile: 64 edges x 320 fp16, 40 units of 16B per edge ----
    {
        const int e = tid >> 2;          // 4 threads per edge
        const int q0 = (tid & 3) * 10;
        const int de = dstI[eb + e];
        const int se = srcI[eb + e];
        const int swz = (e & 7) << 4;
        #pragma unroll
        for (int i = 0; i < 10; ++i) {
            const int q = q0 + i;
            u32x4 v;
            if (q < 16) {
                v = *(const u32x4*)(hhf + (size_t)de * FDIM + q * 8);
            } else if (q < 32) {
                v = *(const u32x4*)(hhf + (size_t)se * FDIM + (q - 16) * 8);
            } else {
                __align__(16) _Float16 tmp[8];
                #pragma unroll
                for (int u = 0; u < 8; ++u) {
                    int col = 256 + (q - 32) * 8 + u;
                    float fv = (col < 297) ? ea[(size_t)(eb + e) * 41 + (col - 256)] : 0.0f;
                    tmp[u] = (_Float16)fv;
                }
                v = *(u32x4*)tmp;
            }
            int addr = e * (ZK * 2) + ((q * 16) ^ swz);
            *(u32x4*)((char*)zs + addr) = v;
        }
    }

    f32x4 acc[4][4];
    #pragma unroll
    for (int m = 0; m < 4; ++m)
        #pragma unroll
        for (int n = 0; n < 4; ++n) acc[m][n] = (f32x4){0.f, 0.f, 0.f, 0.f};

    const int wid = tid >> 6;      // wave col index 0..3
    const int lane = tid & 63;
    const int l15 = lane & 15;
    const int lhi = lane >> 4;     // 0..3

    for (int c = 0; c < NCHUNK; ++c) {
        // stage W chunk c: 16KB linear copy (pre-swizzled in global)
        const u32x4* gw = (const u32x4*)(WgL + (size_t)c * 256 * BKC);
        u32x4* lw = (u32x4*)wt;
        #pragma unroll
        for (int j = 0; j < 4; ++j) lw[tid + 256 * j] = gw[tid + 256 * j];
        __syncthreads();

        // A fragments from z (rows = edges), k = c*32 + lhi*8 + j
        half8 a[4];
        #pragma unroll
        for (int m = 0; m < 4; ++m) {
            int r = m * 16 + l15;
            int kb = c * 64 + lhi * 16;                 // byte offset in row
            a[m] = *(const half8*)((const char*)zs + r * (ZK * 2) + (kb ^ ((r & 7) << 4)));
        }
        #pragma unroll
        for (int n = 0; n < 4; ++n) {
            int col = wid * 64 + n * 16 + l15;
            half8 bfr = *(const half8*)((const char*)wt +
                        col * (BKC * 2) + ((lhi * 16) ^ ((col & 3) << 4)));
            #pragma unroll
            for (int m = 0; m < 4; ++m)
                acc[m][n] = __builtin_amdgcn_mfma_f32_16x16x32_f16(a[m], bfr, acc[m][n], 0, 0, 0);
        }
        __syncthreads();
    }

    // ---- epilogue: m = sigmoid(f) * softplus(s), scatter-add to agg[dst] ----
    #pragma unroll
    for (int p = 0; p < 2; ++p) {
        int feat = wid * 32 + p * 16 + l15;
        float bf_ = biasF[feat];
        float bs_ = biasS[feat];
        #pragma unroll
        for (int m = 0; m < 4; ++m) {
            #pragma unroll
            for (int j = 0; j < 4; ++j) {
                float fp = acc[m][2 * p][j] + bf_;
                float sp = acc[m][2 * p + 1][j] + bs_;
                float sig = 1.0f / (1.0f + __expf(-fp));
                float spl = fmaxf(sp, 0.0f) + log1pf(__expf(-fabsf(sp)));
                float mv = sig * spl;
                int r = m * 16 + lhi * 4 + j;
                atomicAdd(&agg[(size_t)dstl[r] * FDIM + feat], mv);
            }
        }
    }
}

// ---------------- BN_in + residual + BN_out (+outer residual) ----------------
__global__ void node_bn(const float* __restrict__ agg, float* __restrict__ h,
                        _Float16* __restrict__ hhf,
                        const float* __restrict__ gin, const float* __restrict__ bin,
                        const float* __restrict__ min_, const float* __restrict__ vin,
                        const float* __restrict__ gout, const float* __restrict__ bout,
                        const float* __restrict__ mout, const float* __restrict__ vout,
                        int addres, int n128) {
    int idx = blockIdx.x * 256 + threadIdx.x;
    if (idx >= n128) return;
    int f = idx & 127;
    float a = agg[idx];
    a = (a - min_[f]) * (gin[f] / sqrtf(vin[f] + EPSBN)) + bin[f];
    float hv = h[idx];
    float xo = a + hv;
    xo = (xo - mout[f]) * (gout[f] / sqrtf(vout[f] + EPSBN)) + bout[f];
    if (addres) xo += hv;
    h[idx] = xo;
    hhf[idx] = (_Float16)(xo * HSCALE_INV);
}

// ---------------- global mean/max pool via atomics ----------------
__global__ void pool_k(const float* __restrict__ h, const int* __restrict__ batch,
                       float* __restrict__ sums, unsigned* __restrict__ maxs,
                       float* __restrict__ counts, int N) {
    int idx = blockIdx.x * 256 + threadIdx.x;
    if (idx >= N * 128) return;
    int n = idx >> 7, f = idx & 127;
    int g = batch[n];
    float v = h[idx];
    atomicAdd(&sums[g * 128 + f], v);
    unsigned u = __float_as_uint(v);
    unsigned key = (u & 0x80000000u) ? ~u : (u | 0x80000000u);
    atomicMax(&maxs[g * 128 + f], key);
    if (f == 0) atomicAdd(&counts[g], 1.0f);
}

// ---------------- heads: pool-linear + MLPs ----------------
__global__ __launch_bounds__(256)
void head_k(const float* __restrict__ sums, const unsigned* __restrict__ maxs,
            const float* __restrict__ counts,
            const float* __restrict__ pW, const float* __restrict__ pb,
            const float* __restrict__ f1W, const float* __restrict__ f1b,
            const float* __restrict__ f2W, const float* __restrict__ f2b,
            const float* __restrict__ f3W, const float* __restrict__ f3b,
            const float* __restrict__ d1W, const float* __restrict__ d1b,
            const float* __restrict__ d2W, const float* __restrict__ d2b,
            float* __restrict__ out) {
    __shared__ float xp[256], emb[128], s1[256], s2[128], dd[256];
    int g = blockIdx.x, t = threadIdx.x;
    float cnt = counts[g];
    if (t < 128) {
        float mean = sums[g * 128 + t] / fmaxf(cnt, 1.0f);
        float mx = 0.0f;
        if (cnt > 0.0f) {
            unsigned key = maxs[g * 128 + t];
            unsigned u = (key & 0x80000000u) ? (key & 0x7fffffffu) : ~key;
            mx = __uint_as_float(u);
            if (!isfinite(mx)) mx = 0.0f;
        }
        xp[t] = mean;
        xp[128 + t] = mx;
    }
    __syncthreads();
    if (t < 128) {
        float a = pb[t];
        for (int k = 0; k < 256; ++k) a = fmaf(xp[k], pW[k * 128 + t], a);
        emb[t] = fmaxf(a, 0.0f);
    }
    __syncthreads();
    {   // f1: 128 -> 256, silu
        float a = f1b[t];
        for (int k = 0; k < 128; ++k) a = fmaf(emb[k], f1W[k * 256 + t], a);
        s1[t] = a / (1.0f + __expf(-a));
    }
    __syncthreads();
    if (t < 128) {  // f2: 256 -> 128, silu
        float a = f2b[t];
        for (int k = 0; k < 256; ++k) a = fmaf(s1[k], f2W[k * 128 + t], a);
        s2[t] = a / (1.0f + __expf(-a));
    }
    {   // d1: 128 -> 256, silu
        float a = d1b[t];
        for (int k = 0; k < 128; ++k) a = fmaf(emb[k], d1W[k * 256 + t], a);
        dd[t] = a / (1.0f + __expf(-a));
    }
    __syncthreads();
    if (t == 0) {  // formation
        float a = f3b[0];
        for (int k = 0; k < 128; ++k) a = fmaf(s2[k], f3W[k], a);
        out[g] = a;
    }
    for (int o = t; o < 384; o += 256) {  // dos: 256 -> 384
        float a = d2b[o];
        for (int k = 0; k < 256; ++k) a = fmaf(dd[k], d2W[k * 384 + o], a);
        out[128 + (size_t)g * 384 + o] = a;
    }
}

extern "C" void kernel_launch(void* const* d_in, const int* in_sizes, int n_in,
                              void* d_out, int out_size, void* d_ws, size_t ws_size,
                              hipStream_t stream) {
    const float* x       = (const float*)d_in[0];
    const int*   eidx    = (const int*)d_in[1];
    const float* ea      = (const float*)d_in[2];
    const int*   batch   = (const int*)d_in[3];
    const float* embW    = (const float*)d_in[4];
    const float* embB    = (const float*)d_in[5];
    const float* convWf  = (const float*)d_in[6];
    const float* convbf  = (const float*)d_in[7];
    const float* convWs  = (const float*)d_in[8];
    const float* convbs  = (const float*)d_in[9];
    const float* bing    = (const float*)d_in[10];
    const float* binb    = (const float*)d_in[11];
    const float* binm    = (const float*)d_in[12];
    const float* binv    = (const float*)d_in[13];
    const float* bog     = (const float*)d_in[14];
    const float* bob     = (const float*)d_in[15];
    const float* bom     = (const float*)d_in[16];
    const float* bov     = (const float*)d_in[17];
    const float* pW      = (const float*)d_in[18];
    const float* pb      = (const float*)d_in[19];
    const float* f1W     = (const float*)d_in[20];
    const float* f1b     = (const float*)d_in[21];
    const float* f2W     = (const float*)d_in[22];
    const float* f2b     = (const float*)d_in[23];
    const float* f3W     = (const float*)d_in[24];
    const float* f3b     = (const float*)d_in[25];
    const float* d1W     = (const float*)d_in[26];
    const float* d1b     = (const float*)d_in[27];
    const float* d2W     = (const float*)d_in[28];
    const float* d2b     = (const float*)d_in[29];

    const int N = in_sizes[0] / 98;
    const int E = in_sizes[1] / 2;
    const int* srcI = eidx;
    const int* dstI = eidx + E;

    char* ws = (char*)d_ws;
    float* h            = (float*)(ws);                         // N*128*4   = 10,240,000
    float* agg          = (float*)(ws + 10240000);              // N*128*4   = 10,240,000
    _Float16* hhf       = (_Float16*)(ws + 20480000);           // N*128*2   =  5,120,000
    _Float16* Wg        = (_Float16*)(ws + 25600000);           // 983,040
    float* sums         = (float*)(ws + 26583040);              // 65,536
    unsigned* maxs      = (unsigned*)(ws + 26648576);           // 65,536
    float* counts       = (float*)(ws + 26714112);              // 512

    // weight prep (once per call; cheap)
    {
        int total = 6 * NCHUNK * 256 * BKC;
        prep_w<<<(total + 255) / 256, 256, 0, stream>>>(convWf, convWs, Wg);
    }
    embed_k<<<(N + 1) / 2, 256, 0, stream>>>(x, embW, embB, h, hhf, N);

    const int n128 = N * 128;
    for (int i = 0; i < 6; ++i) {
        hipMemsetAsync(agg, 0, (size_t)n128 * 4, stream);
        edge_gemm<<<E / BM, 256, 0, stream>>>(
            hhf, ea, srcI, dstI, Wg + (size_t)i * NCHUNK * 256 * BKC,
            convbf + i * 128, convbs + i * 128, agg);
        node_bn<<<(n128 + 255) / 256, 256, 0, stream>>>(
            agg, h, hhf,
            bing + i * 128, binb + i * 128, binm + i * 128, binv + i * 128,
            bog + i * 128, bob + i * 128, bom + i * 128, bov + i * 128,
            (i > 0) ? 1 : 0, n128);
    }

    hipMemsetAsync(sums, 0, 65536 + 65536 + 512, stream);
    pool_k<<<(n128 + 255) / 256, 256, 0, stream>>>(h, batch, sums, maxs, counts, N);
    head_k<<<128, 256, 0, stream>>>(sums, maxs, counts, pW, pb,
                                    f1W, f1b, f2W, f2b, f3W, f3b,
                                    d1W, d1b, d2W, d2b, (float*)d_out);
}

// Round 5
// 1410.761 us; speedup vs baseline: 1.2156x; 1.2156x over previous
//
#include <hip/hip_runtime.h>
#include <hip/hip_bf16.h>
#include <math.h>

typedef __attribute__((ext_vector_type(8))) _Float16 half8;
typedef __attribute__((ext_vector_type(4))) float f32x4;
typedef __attribute__((ext_vector_type(4))) unsigned int u32x4;

#define FDIM 128
#define EPSBN 1e-5f
#define HSCALE_INV 0.015625f   // h stored as h/64 in fp16
#define WSCALE 64.0f           // node-weight rows pre-scaled (exact pow2)

// ======== weight prep: node part Wn[i][c4][col512][kk] fp16, swizzled ========
// col512 = which*256 + colc ; which=0 -> W rows 0..127 (dst), which=1 -> rows 128..255 (src)
// colc -> (p=(colc>>4)&1 : 0=Wf,1=Ws ; f=((colc>>5)<<4)|(colc&15))
// stored kk holds source k = c4*32 + (kk ^ ((colc&3)<<3)) ; scaled by 64
__global__ void prep_wn(const float* __restrict__ Wf, const float* __restrict__ Ws,
                        _Float16* __restrict__ Wn) {
    int idx = blockIdx.x * 256 + threadIdx.x;
    const int total = 6 * 4 * 512 * 32;
    if (idx >= total) return;
    int kk = idx & 31;
    int col = (idx >> 5) & 511;
    int c4 = (idx >> 14) & 3;
    int i = idx >> 16;
    int which = col >> 8;
    int colc = col & 255;
    int p = (colc >> 4) & 1;
    int f = ((colc >> 5) << 4) | (colc & 15);
    int ksrc = c4 * 32 + (kk ^ ((colc & 3) << 3));
    int row = which * 128 + ksrc;                       // 0..255
    size_t o = ((size_t)i * 297 + row) * 128 + f;
    float v = (p ? Ws[o] : Wf[o]) * WSCALE;
    Wn[idx] = (_Float16)v;
}

// ======== weight prep: edge-attr part Wb[i][c2][colc][kk] fp16, swizzled ========
// source W rows 256..296 (ea), k-local = c2*32 + (kk ^ ((colc&3)<<3)), pad >=41 -> 0. No scale.
__global__ void prep_wb(const float* __restrict__ Wf, const float* __restrict__ Ws,
                        _Float16* __restrict__ Wb) {
    int idx = blockIdx.x * 256 + threadIdx.x;
    const int total = 6 * 2 * 256 * 32;
    if (idx >= total) return;
    int kk = idx & 31;
    int colc = (idx >> 5) & 255;
    int c2 = (idx >> 13) & 1;
    int i = idx >> 14;
    int p = (colc >> 4) & 1;
    int f = ((colc >> 5) << 4) | (colc & 15);
    int kl = c2 * 32 + (kk ^ ((colc & 3) << 3));
    float v = 0.0f;
    if (kl < 41) {
        size_t o = ((size_t)i * 297 + 256 + kl) * 128 + f;
        v = p ? Ws[o] : Wf[o];
    }
    Wb[idx] = (_Float16)v;
}

// ======== embed: h = x @ embed_W + b ========
__global__ void embed_k(const float* __restrict__ x, const float* __restrict__ W,
                        const float* __restrict__ b, float* __restrict__ h,
                        _Float16* __restrict__ hhf, int N) {
    int n = blockIdx.x * 2 + (threadIdx.x >> 7);
    int f = threadIdx.x & 127;
    if (n >= N) return;
    float acc = b[f];
    const float* xr = x + (size_t)n * 98;
    #pragma unroll 7
    for (int k = 0; k < 98; ++k) acc = fmaf(xr[k], W[k * 128 + f], acc);
    h[(size_t)n * 128 + f] = acc;
    hhf[(size_t)n * 128 + f] = (_Float16)(acc * HSCALE_INV);
}

// ======== node GEMM: Pd/Ps = h @ Wtop/Wmid  (32 nodes x 512 cols, K=128) ========
__global__ __launch_bounds__(256, 2)
void node_gemm(const _Float16* __restrict__ hhf, const _Float16* __restrict__ WnL,
               float* __restrict__ Pd, float* __restrict__ Ps, int N) {
    __shared__ __align__(16) _Float16 ht[32 * 128];     // 8 KB, row-swizzled
    __shared__ __align__(16) _Float16 wt[512 * 32];     // 32 KB per k-chunk
    const int tid = threadIdx.x;
    const int nb = blockIdx.x * 32;

    {   // stage h tile: row e = tid>>3, 2 x 16B units
        int e = tid >> 3, t = tid & 7;
        int node = nb + e; if (node >= N) node = N - 1;
        const u32x4* src = (const u32x4*)(hhf + (size_t)node * 128);
        int swz = (e & 7) << 4;
        #pragma unroll
        for (int u = 0; u < 2; ++u) {
            int q = 2 * t + u;
            *(u32x4*)((char*)ht + e * 256 + ((q * 16) ^ swz)) = src[q];
        }
    }

    f32x4 acc[2][8];
    #pragma unroll
    for (int m = 0; m < 2; ++m)
        #pragma unroll
        for (int n = 0; n < 8; ++n) acc[m][n] = (f32x4){0.f, 0.f, 0.f, 0.f};

    const int wid = tid >> 6;
    const int lane = tid & 63;
    const int l15 = lane & 15;
    const int lhi = lane >> 4;
    const int swzA = (l15 & 7) << 4;

    for (int c4 = 0; c4 < 4; ++c4) {
        const u32x4* gw = (const u32x4*)(WnL + (size_t)c4 * 512 * 32);
        #pragma unroll
        for (int j = 0; j < 8; ++j) ((u32x4*)wt)[tid + 256 * j] = gw[tid + 256 * j];
        __syncthreads();

        half8 a[2];
        #pragma unroll
        for (int m = 0; m < 2; ++m) {
            int r = m * 16 + l15;
            a[m] = *(const half8*)((const char*)ht + r * 256 + ((c4 * 64 + lhi * 16) ^ swzA));
        }
        #pragma unroll
        for (int n = 0; n < 8; ++n) {
            int col = wid * 128 + n * 16 + l15;
            half8 b = *(const half8*)((const char*)wt + col * 64 + ((lhi * 16) ^ ((col & 3) << 4)));
            #pragma unroll
            for (int m = 0; m < 2; ++m)
                acc[m][n] = __builtin_amdgcn_mfma_f32_16x16x32_f16(a[m], b, acc[m][n], 0, 0, 0);
        }
        __syncthreads();
    }

    #pragma unroll
    for (int m = 0; m < 2; ++m) {
        #pragma unroll
        for (int n = 0; n < 8; ++n) {
            int col512 = wid * 128 + n * 16 + l15;
            float* base = (col512 < 256) ? Pd : Ps;
            int c = col512 & 255;
            #pragma unroll
            for (int j = 0; j < 4; ++j) {
                int node = nb + m * 16 + lhi * 4 + j;
                if (node < N) base[(size_t)node * 256 + c] = acc[m][n][j];
            }
        }
    }
}

// ======== edge kernel: ea GEMM (K=64) + Pd/Ps gather + gate + scatter-add ========
__global__ __launch_bounds__(256, 3)
void edge_v2(const float* __restrict__ ea,
             const int* __restrict__ srcI, const int* __restrict__ dstI,
             const _Float16* __restrict__ WbL,      // [2][256][32] fp16 swizzled
             const float* __restrict__ Pd, const float* __restrict__ Ps,
             const float* __restrict__ biasF, const float* __restrict__ biasS,
             float* __restrict__ agg) {
    __shared__ __align__(16) _Float16 eat[64 * 64];    // 8 KB, row-swizzled
    __shared__ __align__(16) _Float16 wb[2 * 256 * 32]; // 32 KB
    __shared__ int dstl[64], srcl[64];

    const int tid = threadIdx.x;
    const int eb = blockIdx.x * 64;

    if (tid < 64) dstl[tid] = dstI[eb + tid];
    else if (tid < 128) srcl[tid - 64] = srcI[eb + tid - 64];

    {   // stage ea tile: e = tid>>2 ; quad t covers fp16 cols t*16..t*16+15
        int e = tid >> 2, t = tid & 3;
        const float* row = ea + (size_t)(eb + e) * 41;
        __align__(16) _Float16 tmp[16];
        #pragma unroll
        for (int u = 0; u < 16; ++u) {
            int cc = t * 16 + u;
            tmp[u] = (cc < 41) ? (_Float16)row[cc] : (_Float16)0.f;
        }
        int swz = (e & 7) << 4;
        *(u32x4*)((char*)eat + e * 128 + (((2 * t) * 16) ^ swz)) = *(u32x4*)tmp;
        *(u32x4*)((char*)eat + e * 128 + (((2 * t + 1) * 16) ^ swz)) = *(u32x4*)(tmp + 8);
    }
    {   // stage Wb: 32 KB linear
        const u32x4* gw = (const u32x4*)WbL;
        #pragma unroll
        for (int j = 0; j < 8; ++j) ((u32x4*)wb)[tid + 256 * j] = gw[tid + 256 * j];
    }
    __syncthreads();   // single barrier; LDS read-only afterwards

    f32x4 acc[4][4];
    #pragma unroll
    for (int m = 0; m < 4; ++m)
        #pragma unroll
        for (int n = 0; n < 4; ++n) acc[m][n] = (f32x4){0.f, 0.f, 0.f, 0.f};

    const int wid = tid >> 6;
    const int lane = tid & 63;
    const int l15 = lane & 15;
    const int lhi = lane >> 4;
    const int swzA = (l15 & 7) << 4;

    #pragma unroll
    for (int c2 = 0; c2 < 2; ++c2) {
        half8 a[4];
        #pragma unroll
        for (int m = 0; m < 4; ++m) {
            int r = m * 16 + l15;
            a[m] = *(const half8*)((const char*)eat + r * 128 + ((c2 * 64 + lhi * 16) ^ swzA));
        }
        #pragma unroll
        for (int n = 0; n < 4; ++n) {
            int col = wid * 64 + n * 16 + l15;
            half8 b = *(const half8*)((const char*)wb + ((c2 << 8) + col) * 64 +
                                      ((lhi * 16) ^ ((col & 3) << 4)));
            #pragma unroll
            for (int m = 0; m < 4; ++m)
                acc[m][n] = __builtin_amdgcn_mfma_f32_16x16x32_f16(a[m], b, acc[m][n], 0, 0, 0);
        }
    }

    // epilogue: out = acc + Pd[dst] + Ps[src] + bias ; m = sigmoid(f)*softplus(s)
    const int cF0 = wid * 64 + l15;          // f-col for p=0 ; +16 -> s-col ; +32 -> p=1
    const int feat0 = wid * 32 + l15;        // feature id for p=0 ; +16 -> p=1
    const float bF0 = biasF[feat0], bF1 = biasF[feat0 + 16];
    const float bS0 = biasS[feat0], bS1 = biasS[feat0 + 16];

    #pragma unroll
    for (int m = 0; m < 4; ++m) {
        #pragma unroll
        for (int j = 0; j < 4; ++j) {
            int r = m * 16 + lhi * 4 + j;
            int dn = dstl[r], sn = srcl[r];
            const float* pd = Pd + (size_t)dn * 256;
            const float* ps = Ps + (size_t)sn * 256;
            float* ag = agg + (size_t)dn * 128;
            #pragma unroll
            for (int p = 0; p < 2; ++p) {
                int cF = cF0 + 32 * p;
                float fp = acc[m][2 * p][j] + pd[cF] + ps[cF] + (p ? bF1 : bF0);
                float sp = acc[m][2 * p + 1][j] + pd[cF + 16] + ps[cF + 16] + (p ? bS1 : bS0);
                float sig = 1.0f / (1.0f + __expf(-fp));
                float spl = fmaxf(sp, 0.0f) + __logf(1.0f + __expf(-fabsf(sp)));
                atomicAdd(ag + feat0 + 16 * p, sig * spl);
            }
        }
    }
}

// ======== BN_in + residual + BN_out (+outer residual) ========
__global__ void node_bn(const float* __restrict__ agg, float* __restrict__ h,
                        _Float16* __restrict__ hhf,
                        const float* __restrict__ gin, const float* __restrict__ bin,
                        const float* __restrict__ min_, const float* __restrict__ vin,
                        const float* __restrict__ gout, const float* __restrict__ bout,
                        const float* __restrict__ mout, const float* __restrict__ vout,
                        int addres, int n128) {
    int idx = blockIdx.x * 256 + threadIdx.x;
    if (idx >= n128) return;
    int f = idx & 127;
    float a = agg[idx];
    a = (a - min_[f]) * (gin[f] / sqrtf(vin[f] + EPSBN)) + bin[f];
    float hv = h[idx];
    float xo = a + hv;
    xo = (xo - mout[f]) * (gout[f] / sqrtf(vout[f] + EPSBN)) + bout[f];
    if (addres) xo += hv;
    h[idx] = xo;
    hhf[idx] = (_Float16)(xo * HSCALE_INV);
}

// ======== global mean/max pool via atomics ========
__global__ void pool_k(const float* __restrict__ h, const int* __restrict__ batch,
                       float* __restrict__ sums, unsigned* __restrict__ maxs,
                       float* __restrict__ counts, int N) {
    int idx = blockIdx.x * 256 + threadIdx.x;
    if (idx >= N * 128) return;
    int n = idx >> 7, f = idx & 127;
    int g = batch[n];
    float v = h[idx];
    atomicAdd(&sums[g * 128 + f], v);
    unsigned u = __float_as_uint(v);
    unsigned key = (u & 0x80000000u) ? ~u : (u | 0x80000000u);
    atomicMax(&maxs[g * 128 + f], key);
    if (f == 0) atomicAdd(&counts[g], 1.0f);
}

// ======== heads ========
__global__ __launch_bounds__(256)
void head_k(const float* __restrict__ sums, const unsigned* __restrict__ maxs,
            const float* __restrict__ counts,
            const float* __restrict__ pW, const float* __restrict__ pb,
            const float* __restrict__ f1W, const float* __restrict__ f1b,
            const float* __restrict__ f2W, const float* __restrict__ f2b,
            const float* __restrict__ f3W, const float* __restrict__ f3b,
            const float* __restrict__ d1W, const float* __restrict__ d1b,
            const float* __restrict__ d2W, const float* __restrict__ d2b,
            float* __restrict__ out) {
    __shared__ float xp[256], emb[128], s1[256], s2[128], dd[256];
    int g = blockIdx.x, t = threadIdx.x;
    float cnt = counts[g];
    if (t < 128) {
        float mean = sums[g * 128 + t] / fmaxf(cnt, 1.0f);
        float mx = 0.0f;
        if (cnt > 0.0f) {
            unsigned key = maxs[g * 128 + t];
            unsigned u = (key & 0x80000000u) ? (key & 0x7fffffffu) : ~key;
            mx = __uint_as_float(u);
            if (!isfinite(mx)) mx = 0.0f;
        }
        xp[t] = mean;
        xp[128 + t] = mx;
    }
    __syncthreads();
    if (t < 128) {
        float a = pb[t];
        for (int k = 0; k < 256; ++k) a = fmaf(xp[k], pW[k * 128 + t], a);
        emb[t] = fmaxf(a, 0.0f);
    }
    __syncthreads();
    {
        float a = f1b[t];
        for (int k = 0; k < 128; ++k) a = fmaf(emb[k], f1W[k * 256 + t], a);
        s1[t] = a / (1.0f + __expf(-a));
    }
    __syncthreads();
    if (t < 128) {
        float a = f2b[t];
        for (int k = 0; k < 256; ++k) a = fmaf(s1[k], f2W[k * 128 + t], a);
        s2[t] = a / (1.0f + __expf(-a));
    }
    {
        float a = d1b[t];
        for (int k = 0; k < 128; ++k) a = fmaf(emb[k], d1W[k * 256 + t], a);
        dd[t] = a / (1.0f + __expf(-a));
    }
    __syncthreads();
    if (t == 0) {
        float a = f3b[0];
        for (int k = 0; k < 128; ++k) a = fmaf(s2[k], f3W[k], a);
        out[g] = a;
    }
    for (int o = t; o < 384; o += 256) {
        float a = d2b[o];
        for (int k = 0; k < 256; ++k) a = fmaf(dd[k], d2W[k * 384 + o], a);
        out[128 + (size_t)g * 384 + o] = a;
    }
}

extern "C" void kernel_launch(void* const* d_in, const int* in_sizes, int n_in,
                              void* d_out, int out_size, void* d_ws, size_t ws_size,
                              hipStream_t stream) {
    const float* x       = (const float*)d_in[0];
    const int*   eidx    = (const int*)d_in[1];
    const float* ea      = (const float*)d_in[2];
    const int*   batch   = (const int*)d_in[3];
    const float* embW    = (const float*)d_in[4];
    const float* embB    = (const float*)d_in[5];
    const float* convWf  = (const float*)d_in[6];
    const float* convbf  = (const float*)d_in[7];
    const float* convWs  = (const float*)d_in[8];
    const float* convbs  = (const float*)d_in[9];
    const float* bing    = (const float*)d_in[10];
    const float* binb    = (const float*)d_in[11];
    const float* binm    = (const float*)d_in[12];
    const float* binv    = (const float*)d_in[13];
    const float* bog     = (const float*)d_in[14];
    const float* bob     = (const float*)d_in[15];
    const float* bom     = (const float*)d_in[16];
    const float* bov     = (const float*)d_in[17];
    const float* pW      = (const float*)d_in[18];
    const float* pb      = (const float*)d_in[19];
    const float* f1W     = (const float*)d_in[20];
    const float* f1b     = (const float*)d_in[21];
    const float* f2W     = (const float*)d_in[22];
    const float* f2b     = (const float*)d_in[23];
    const float* f3W     = (const float*)d_in[24];
    const float* f3b     = (const float*)d_in[25];
    const float* d1W     = (const float*)d_in[26];
    const float* d1b     = (const float*)d_in[27];
    const float* d2W     = (const float*)d_in[28];
    const float* d2b     = (const float*)d_in[29];

    const int N = in_sizes[0] / 98;
    const int E = in_sizes[1] / 2;
    const int* srcI = eidx;
    const int* dstI = eidx + E;

    char* ws = (char*)d_ws;
    float* h            = (float*)(ws);                         // 10,240,000
    float* agg          = (float*)(ws + 10240000);              // 10,240,000
    _Float16* hhf       = (_Float16*)(ws + 20480000);           //  5,120,000
    float* Pd           = (float*)(ws + 25600000);              // 20,480,000
    float* Ps           = (float*)(ws + 46080000);              // 20,480,000
    _Float16* Wn        = (_Float16*)(ws + 66560000);           //    786,432
    _Float16* Wb        = (_Float16*)(ws + 67346432);           //    196,608
    float* sums         = (float*)(ws + 67543040);              //     65,536
    unsigned* maxs      = (unsigned*)(ws + 67608576);           //     65,536
    float* counts       = (float*)(ws + 67674112);              //        512

    prep_wn<<<(6 * 4 * 512 * 32) / 256, 256, 0, stream>>>(convWf, convWs, Wn);
    prep_wb<<<(6 * 2 * 256 * 32) / 256, 256, 0, stream>>>(convWf, convWs, Wb);
    embed_k<<<(N + 1) / 2, 256, 0, stream>>>(x, embW, embB, h, hhf, N);

    const int n128 = N * 128;
    const int nblk = (N + 31) / 32;
    for (int i = 0; i < 6; ++i) {
        node_gemm<<<nblk, 256, 0, stream>>>(hhf, Wn + (size_t)i * 4 * 512 * 32, Pd, Ps, N);
        hipMemsetAsync(agg, 0, (size_t)n128 * 4, stream);
        edge_v2<<<E / 64, 256, 0, stream>>>(ea, srcI, dstI,
                                            Wb + (size_t)i * 2 * 256 * 32,
                                            Pd, Ps, convbf + i * 128, convbs + i * 128, agg);
        node_bn<<<(n128 + 255) / 256, 256, 0, stream>>>(
            agg, h, hhf,
            bing + i * 128, binb + i * 128, binm + i * 128, binv + i * 128,
            bog + i * 128, bob + i * 128, bom + i * 128, bov + i * 128,
            (i > 0) ? 1 : 0, n128);
    }

    hipMemsetAsync(sums, 0, 65536 + 65536 + 512, stream);
    pool_k<<<(n128 + 255) / 256, 256, 0, stream>>>(h, batch, sums, maxs, counts, N);
    head_k<<<128, 256, 0, stream>>>(sums, maxs, counts, pW, pb,
                                    f1W, f1b, f2W, f2b, f3W, f3b,
                                    d1W, d1b, d2W, d2b, (float*)d_out);
}